// Round 2
// baseline (31798.712 us; speedup 1.0000x reference)
//
#include <hip/hip_runtime.h>

#define NB 8
#define NS 2048
#define ND 1024
#define NH 1024
#define NWG 256
#define TPB 256
#define HPW 4   /* h-coords per workgroup: NH / NWG */

#define SCOPE_AGENT __HIP_MEMORY_SCOPE_AGENT

__device__ __forceinline__ float sigmf(float v)     { return 1.f / (1.f + __expf(-v)); }
__device__ __forceinline__ float tanh_fast(float v) { return 1.f - 2.f / (1.f + __expf(2.f * v)); }

#define DOT4(acc, W, V)                 \
    acc = fmaf((W).x, (V).x, acc);      \
    acc = fmaf((W).y, (V).y, acc);      \
    acc = fmaf((W).z, (V).z, acc);      \
    acc = fmaf((W).w, (V).w, acc);

// Two-level grid barrier: 8 groups x 32 WGs. Called by tid==0 only.
__device__ __forceinline__ void grid_barrier(unsigned* bar, int grp, unsigned target) {
    unsigned prev = __hip_atomic_fetch_add(bar + grp * 32, 1u, __ATOMIC_ACQ_REL, SCOPE_AGENT);
    if (prev == 31u) {
        unsigned p2 = __hip_atomic_fetch_add(bar + 300, 1u, __ATOMIC_ACQ_REL, SCOPE_AGENT);
        if (p2 == 7u) {
            // last WG on the device: reset counters, then release everyone
            #pragma unroll
            for (int g = 0; g < 8; ++g)
                __hip_atomic_store(bar + g * 32, 0u, __ATOMIC_RELAXED, SCOPE_AGENT);
            __hip_atomic_store(bar + 300, 0u, __ATOMIC_RELAXED, SCOPE_AGENT);
            #pragma unroll
            for (int g = 0; g < 8; ++g)
                __hip_atomic_store(bar + 512 + g * 32, target, __ATOMIC_RELEASE, SCOPE_AGENT);
            return;
        }
    }
    while (__hip_atomic_load(bar + 512 + grp * 32, __ATOMIC_RELAXED, SCOPE_AGENT) < target)
        __builtin_amdgcn_s_sleep(2);
    __builtin_amdgcn_fence(__ATOMIC_ACQUIRE, "agent");
}

__global__ __launch_bounds__(TPB, 1)
void scan_kernel(const float* __restrict__ x,
                 const float* __restrict__ w_ih,
                 const float* __restrict__ w_hh,
                 const float* __restrict__ b_ih,
                 const float* __restrict__ b_hh,
                 const float* __restrict__ thrp,
                 float* __restrict__ membuf,           // 2 * NB*NH floats (double buffer)
                 unsigned long long* __restrict__ bitmap, // NB*NS*(NH/64) words
                 unsigned* __restrict__ bar,
                 float* __restrict__ out_syn,
                 float* __restrict__ out_mem)
{
    __shared__ float x_s[NB * NH];     // 32 KB: x[:, t, :]
    __shared__ float m_s[NB * NH];     // 32 KB: mem(t-1)
    __shared__ float sg[16 * NB];      // gate pre-activations for this WG's 4 h-coords
    __shared__ float c_s[HPW * NB];    // persistent cell state slice

    const int tid  = threadIdx.x;
    const int wg   = blockIdx.x;
    const int hb   = wg * HPW;
    const int wave = tid >> 6;         // 0..3 -> gate index (i,f,g,o)
    const int lane = tid & 63;
    const int grp  = wg >> 5;
    const float thr = *thrp;

    if (tid < HPW * NB) c_s[tid] = 0.f;

    // Register-stationary weights: wave w owns gate w, rows r = w*NH + hb + hh.
    // Lane l owns k-slice {j*256 + l*4 .. +3 | j=0..3} of both w_ih and w_hh rows.
    float4 wih[4][4], whh[4][4];
    float bias[4];
    #pragma unroll
    for (int hh = 0; hh < 4; ++hh) {
        const int r = wave * NH + hb + hh;
        #pragma unroll
        for (int j = 0; j < 4; ++j) {
            wih[hh][j] = *(const float4*)(w_ih + (size_t)r * ND + j * 256 + lane * 4);
            whh[hh][j] = *(const float4*)(w_hh + (size_t)r * NH + j * 256 + lane * 4);
        }
        bias[hh] = b_ih[r] + b_hh[r];
    }

    unsigned target = 0;

    for (int t = 0; t < NS; ++t) {
        const float* mcur = membuf + (size_t)(t & 1) * (NB * NH);
        float*       mnxt = membuf + (size_t)((t + 1) & 1) * (NB * NH);

        // ---- stage x_t (plain, read-only input) and mem (agent-scope atomic) into LDS
        #pragma unroll
        for (int i = 0; i < 16; ++i) {
            int f4 = tid + i * TPB;               // 0..4095 float4 slots
            if (f4 < 2048) {
                int b = f4 >> 8, d4 = (f4 & 255) * 4;
                *(float4*)(x_s + b * NH + d4) =
                    *(const float4*)(x + ((size_t)b * NS + t) * ND + d4);
            } else {
                int f = f4 - 2048;
                int b = f >> 8, d4 = (f & 255) * 4;
                unsigned* src = (unsigned*)(mcur + b * NH + d4);
                float4 v;
                v.x = __uint_as_float(__hip_atomic_load(src + 0, __ATOMIC_RELAXED, SCOPE_AGENT));
                v.y = __uint_as_float(__hip_atomic_load(src + 1, __ATOMIC_RELAXED, SCOPE_AGENT));
                v.z = __uint_as_float(__hip_atomic_load(src + 2, __ATOMIC_RELAXED, SCOPE_AGENT));
                v.w = __uint_as_float(__hip_atomic_load(src + 3, __ATOMIC_RELAXED, SCOPE_AGENT));
                *(float4*)(m_s + b * NH + d4) = v;
            }
        }
        __syncthreads();

        // ---- gate dot products: 4 rows/wave x 8 batches, K=2048 (x part + mem part)
        for (int b = 0; b < NB; ++b) {
            float4 xv[4], mv[4];
            #pragma unroll
            for (int j = 0; j < 4; ++j) {
                xv[j] = *(const float4*)(x_s + b * NH + j * 256 + lane * 4);
                mv[j] = *(const float4*)(m_s + b * NH + j * 256 + lane * 4);
            }
            float a0 = 0.f, a1 = 0.f, a2 = 0.f, a3 = 0.f;
            #pragma unroll
            for (int j = 0; j < 4; ++j) {
                DOT4(a0, wih[0][j], xv[j]); DOT4(a0, whh[0][j], mv[j]);
                DOT4(a1, wih[1][j], xv[j]); DOT4(a1, whh[1][j], mv[j]);
                DOT4(a2, wih[2][j], xv[j]); DOT4(a2, whh[2][j], mv[j]);
                DOT4(a3, wih[3][j], xv[j]); DOT4(a3, whh[3][j], mv[j]);
            }
            #pragma unroll
            for (int off = 32; off >= 1; off >>= 1) {
                a0 += __shfl_xor(a0, off);
                a1 += __shfl_xor(a1, off);
                a2 += __shfl_xor(a2, off);
                a3 += __shfl_xor(a3, off);
            }
            if (lane == 0) {
                sg[(wave * 4 + 0) * NB + b] = a0 + bias[0];
                sg[(wave * 4 + 1) * NB + b] = a1 + bias[1];
                sg[(wave * 4 + 2) * NB + b] = a2 + bias[2];
                sg[(wave * 4 + 3) * NB + b] = a3 + bias[3];
            }
        }
        __syncthreads();

        // ---- pointwise LSTM update for this WG's 4 h-coords x 8 batches
        if (tid < HPW * NB) {
            const int hh = tid >> 3, b = tid & 7;
            const int h  = hb + hh;
            // sg index: (gate*4 + hh)*NB + b ; gate order i,f,g,o
            float gi_v = sg[(0 * 4 + hh) * NB + b];
            float gf_v = sg[(1 * 4 + hh) * NB + b];
            float gg_v = sg[(2 * 4 + hh) * NB + b];
            float go_v = sg[(3 * 4 + hh) * NB + b];
            float c  = c_s[tid];
            float cn = sigmf(gf_v) * c + sigmf(gi_v) * tanh_fast(gg_v);
            float hv = sigmf(go_v) * tanh_fast(cn);
            float mprev = m_s[b * NH + h];
            float reset = (mprev - thr > 0.f) ? 1.f : 0.f;   // snntorch mem_reset (prev mem)
            float mn = hv - reset * thr;
            c_s[tid] = cn;
            __hip_atomic_store((unsigned*)(mnxt + b * NH + h), __float_as_uint(mn),
                               __ATOMIC_RELAXED, SCOPE_AGENT);
            if (mn - thr > 0.f)   // spike (never fires for this data since |hv|<1, but honest)
                atomicOr(bitmap + (size_t)(b * NS + t) * (NH / 64) + (h >> 6),
                         1ull << (h & 63));
            if (t == NS - 1) {
                out_syn[b * NH + h] = cn;
                out_mem[b * NH + h] = mn;
            }
        }
        __syncthreads();

        if (t < NS - 1) {
            if (tid == 0) {
                ++target;
                grid_barrier(bar, grp, target);
            }
            __syncthreads();
        }
    }
}

// out[b,s,:] = dyt_w * tanh(alpha * (x + b_fc + spk @ w_fc^T)) + dyt_b
__global__ __launch_bounds__(TPB)
void out_kernel(const float* __restrict__ x,
                const float* __restrict__ b_fc,
                const float* __restrict__ w_fc,
                const float* __restrict__ alphap,
                const float* __restrict__ dytw,
                const float* __restrict__ dytb,
                const unsigned long long* __restrict__ bitmap,
                float* __restrict__ out)
{
    __shared__ unsigned long long wds[16];
    __shared__ int flag;
    const int row = blockIdx.x;      // b*NS + s
    const int tid = threadIdx.x;
    if (tid < 16) wds[tid] = bitmap[(size_t)row * 16 + tid];
    __syncthreads();
    if (tid == 0) {
        unsigned long long o = 0ull;
        #pragma unroll
        for (int i = 0; i < 16; ++i) o |= wds[i];
        flag = (o != 0ull);
    }
    __syncthreads();

    const float alpha = *alphap;
    const float* xr = x + (size_t)row * NH;
    float* orow = out + (size_t)row * NH;
    const int j0 = tid * 4;

    float4 xv = *(const float4*)(xr + j0);
    float4 bf = *(const float4*)(b_fc + j0);
    float4 dw = *(const float4*)(dytw + j0);
    float4 db = *(const float4*)(dytb + j0);
    float p[4]   = {xv.x, xv.y, xv.z, xv.w};
    float bfa[4] = {bf.x, bf.y, bf.z, bf.w};
    float dwa[4] = {dw.x, dw.y, dw.z, dw.w};
    float dba[4] = {db.x, db.y, db.z, db.w};

    #pragma unroll
    for (int u = 0; u < 4; ++u) {
        float v = p[u] + bfa[u];
        if (flag) {   // general spike path (block-uniform branch; cold on this data)
            const int j = j0 + u;
            for (int wi = 0; wi < 16; ++wi) {
                unsigned long long m = wds[wi];
                while (m) {
                    int bit = __ffsll(m) - 1;
                    m &= m - 1;
                    v += w_fc[(size_t)j * NH + wi * 64 + bit];
                }
            }
        }
        p[u] = dwa[u] * tanh_fast(alpha * v) + dba[u];
    }
    *(float4*)(orow + j0) = make_float4(p[0], p[1], p[2], p[3]);
}

extern "C" void kernel_launch(void* const* d_in, const int* in_sizes, int n_in,
                              void* d_out, int out_size, void* d_ws, size_t ws_size,
                              hipStream_t stream) {
    const float* x     = (const float*)d_in[0];
    const float* w_ih  = (const float*)d_in[1];
    const float* w_hh  = (const float*)d_in[2];
    const float* b_ih  = (const float*)d_in[3];
    const float* b_hh  = (const float*)d_in[4];
    const float* w_fc  = (const float*)d_in[5];
    const float* b_fc  = (const float*)d_in[6];
    const float* thr   = (const float*)d_in[7];
    const float* alpha = (const float*)d_in[8];
    const float* dytw  = (const float*)d_in[9];
    const float* dytb  = (const float*)d_in[10];

    float* out  = (float*)d_out;
    float* syn  = out + (size_t)NB * NS * NH;
    float* memf = syn + (size_t)NB * NH;

    char* ws = (char*)d_ws;
    unsigned* bar   = (unsigned*)ws;                                  // 4 KB barrier region
    float* membuf   = (float*)(ws + 4096);                            // 64 KB double buffer
    unsigned long long* bitmap = (unsigned long long*)(ws + 4096 + 2 * NB * NH * 4);

    size_t zbytes = 4096 + (size_t)2 * NB * NH * 4
                  + (size_t)NB * NS * (NH / 64) * 8;                  // ~2.17 MB
    (void)hipMemsetAsync(d_ws, 0, zbytes, stream);

    hipLaunchKernelGGL(scan_kernel, dim3(NWG), dim3(TPB), 0, stream,
                       x, w_ih, w_hh, b_ih, b_hh, thr, membuf, bitmap, bar, syn, memf);
    hipLaunchKernelGGL(out_kernel, dim3(NB * NS), dim3(TPB), 0, stream,
                       x, b_fc, w_fc, alpha, dytw, dytb, bitmap, out);
}